// Round 17
// baseline (4508.992 us; speedup 1.0000x reference)
//
#include <hip/hip_runtime.h>
#include <math.h>

#define NITEMS 50000
#define NROWS 50001
#define NP 50176          // padded row count (392*128)
#define DD 512
#define HH 512
#define TT 16
#define NEGV (-1e18f)
#define NGRP 784          // 392 groups x 2 partials
#define NSB 512           // k_step blocks

typedef unsigned long long ull;
typedef unsigned short ushort;
typedef short short8 __attribute__((ext_vector_type(8)));
typedef float f32x4 __attribute__((ext_vector_type(4)));

#define AST(p, v) __hip_atomic_store((p), (v), __ATOMIC_RELAXED, __HIP_MEMORY_SCOPE_AGENT)
#define ALD(p) __hip_atomic_load((p), __ATOMIC_RELAXED, __HIP_MEMORY_SCOPE_AGENT)
#define AADD_REL(p) __hip_atomic_fetch_add((p), 1u, __ATOMIC_ACQ_REL, __HIP_MEMORY_SCOPE_AGENT)
#define FLAG_SET(p) __hip_atomic_store((p), 1u, __ATOMIC_RELEASE, __HIP_MEMORY_SCOPE_AGENT)
#define FLAG_GET(p) __hip_atomic_load((p), __ATOMIC_ACQUIRE, __HIP_MEMORY_SCOPE_AGENT)

__device__ __forceinline__ unsigned fkey(float f) {
  unsigned u = __float_as_uint(f);
  return (u & 0x80000000u) ? ~u : (u | 0x80000000u);
}
__device__ __forceinline__ float ftanh(float x) {
  float e = __builtin_amdgcn_exp2f(x * 2.885390081777927f);
  return 1.f - 2.f * __builtin_amdgcn_rcpf(e + 1.f);
}
__device__ __forceinline__ float fexp(float x) {
  return __builtin_amdgcn_exp2f(x * 1.4426950408889634f);
}
__device__ __forceinline__ ushort rne1(float a) {
  unsigned u = __float_as_uint(a);
  return (ushort)((u + 0x7fffu + ((u >> 16) & 1u)) >> 16);
}
__device__ __forceinline__ float bf2f(ushort h) { return __uint_as_float((unsigned)h << 16); }
__device__ __forceinline__ unsigned pack_bf16(float a, float b) {
  return (unsigned)rne1(a) | ((unsigned)rne1(b) << 16);
}
__device__ __forceinline__ float bflo(unsigned u) { return __uint_as_float(u << 16); }
__device__ __forceinline__ float bfhi(unsigned u) { return __uint_as_float(u & 0xffff0000u); }

__device__ __forceinline__ void gl_lds16(const void* g, void* l) {
#if __has_builtin(__builtin_amdgcn_global_load_lds)
  __builtin_amdgcn_global_load_lds((const __attribute__((address_space(1))) unsigned*)g,
                                   (__attribute__((address_space(3))) unsigned*)l, 16, 0, 0);
#else
  const int lane = threadIdx.x & 63;
  *(uint4*)((char*)l + lane * 16) = *(const uint4*)g;
#endif
}

#define MFMA(a, b, c) __builtin_amdgcn_mfma_f32_16x16x32_bf16(a, b, c, 0, 0, 0)

// ---------------- A -> (Ahi, Alo) bf16 [NP][512] ----------------
__global__ void k_convA(const float* __restrict__ A0, const float* __restrict__ stoprow,
                        ushort* __restrict__ Ahi, ushort* __restrict__ Alo) {
  const size_t t = (size_t)blockIdx.x * 256 + threadIdx.x;
  const size_t base = t * 8;
  const int row = (int)(base >> 9);
  float v[8];
  if (row < NITEMS) {
    const float4* p = (const float4*)(A0 + base);
    float4 x = p[0], y = p[1];
    v[0] = x.x; v[1] = x.y; v[2] = x.z; v[3] = x.w;
    v[4] = y.x; v[5] = y.y; v[6] = y.z; v[7] = y.w;
  } else if (row == NITEMS) {
    const float4* p = (const float4*)(stoprow + (base & 511));
    float4 x = p[0], y = p[1];
    v[0] = x.x; v[1] = x.y; v[2] = x.z; v[3] = x.w;
    v[4] = y.x; v[5] = y.y; v[6] = y.z; v[7] = y.w;
  } else {
#pragma unroll
    for (int j = 0; j < 8; ++j) v[j] = 0.f;
  }
  unsigned hw[4], lw[4];
#pragma unroll
  for (int j = 0; j < 4; ++j) {
    float a0 = v[2 * j], a1 = v[2 * j + 1];
    ushort h0 = rne1(a0), h1 = rne1(a1);
    hw[j] = (unsigned)h0 | ((unsigned)h1 << 16);
    lw[j] = pack_bf16(a0 - bf2f(h0), a1 - bf2f(h1));
  }
  *(uint4*)(Ahi + base) = make_uint4(hw[0], hw[1], hw[2], hw[3]);
  *(uint4*)(Alo + base) = make_uint4(lw[0], lw[1], lw[2], lw[3]);
}

// ---------------- W [k][n] -> transposed bf16 ----------------
__global__ void k_convBT(const float* __restrict__ W, ushort* __restrict__ WhiT,
                         ushort* __restrict__ WloT) {
  const int n = blockIdx.x;
  const int k0 = threadIdx.x * 2;
  float a0 = W[(size_t)k0 * 512 + n];
  float a1 = W[(size_t)(k0 + 1) * 512 + n];
  ushort h0 = rne1(a0), h1 = rne1(a1);
  *(unsigned*)(WhiT + (size_t)n * 512 + k0) = (unsigned)h0 | ((unsigned)h1 << 16);
  *(unsigned*)(WloT + (size_t)n * 512 + k0) = pack_bf16(a0 - bf2f(h0), a1 - bf2f(h1));
}

// ---------------- MFMA GEMM (verified R10; TR=1 only; 1568 = 8*196 swizzle) ----------------
__launch_bounds__(256, 2)
__global__ void k_mfma(const ushort* __restrict__ Ahi, const ushort* __restrict__ Alo,
                       const ushort* __restrict__ BhT, const ushort* __restrict__ BlT,
                       ushort* __restrict__ C) {
  __shared__ __align__(16) char lds[65536];
  char* sA0 = lds;
  char* sA1 = lds + 16384;
  char* sB0 = lds + 32768;
  char* sB1 = lds + 49152;
  const int tid = threadIdx.x;
  const int lane = tid & 63, w = tid >> 6;
  const int lid = blockIdx.y * 4 + blockIdx.x;
  const int xcd = lid & 7, pos = lid >> 3;
  const int orig = xcd * 196 + pos;
  const int m0 = (orig >> 2) * 128, n0 = (orig & 3) * 128;
  const int aR0 = (w & 1) * 64, bR0 = (w >> 1) * 64;

  f32x4 acc[4][4];
  const f32x4 z4 = {0.f, 0.f, 0.f, 0.f};
#pragma unroll
  for (int i = 0; i < 4; ++i)
#pragma unroll
    for (int j = 0; j < 4; ++j) acc[i][j] = z4;

#define STAGE_ALL(KT)                                                                     \
  {                                                                                       \
    _Pragma("unroll") for (int i = 0; i < 4; ++i) {                                       \
      const int row = i * 32 + (tid >> 3);                                                \
      const int kb = ((tid & 7) << 4) ^ ((row & 7) << 4);                                 \
      const int ldso = i * 4096 + (w << 10);                                              \
      gl_lds16((const char*)(Ahi + ((size_t)(m0 + row) << 9) + (KT)) + kb, sA0 + ldso);   \
      gl_lds16((const char*)(Alo + ((size_t)(m0 + row) << 9) + (KT)) + kb, sA1 + ldso);   \
      gl_lds16((const char*)(BhT + ((size_t)(n0 + row) << 9) + (KT)) + kb, sB0 + ldso);   \
      gl_lds16((const char*)(BlT + ((size_t)(n0 + row) << 9) + (KT)) + kb, sB1 + ldso);   \
    }                                                                                     \
  }

  STAGE_ALL(0)
  __syncthreads();
  for (int c = 0; c < 8; ++c) {
#pragma unroll
    for (int ks = 0; ks < 2; ++ks) {
      short8 ah[4], al[4], bh[4], bl[4];
      const int kbb = ks * 64 + ((lane >> 4) << 4);
#pragma unroll
      for (int f = 0; f < 4; ++f) {
        const int ra = aR0 + f * 16 + (lane & 15);
        const int oa = ra * 128 + (kbb ^ ((ra & 7) << 4));
        ah[f] = *(const short8*)(sA0 + oa);
        al[f] = *(const short8*)(sA1 + oa);
        const int rb = bR0 + f * 16 + (lane & 15);
        const int ob = rb * 128 + (kbb ^ ((rb & 7) << 4));
        bh[f] = *(const short8*)(sB0 + ob);
        bl[f] = *(const short8*)(sB1 + ob);
      }
#pragma unroll
      for (int mf = 0; mf < 4; ++mf)
#pragma unroll
        for (int nf = 0; nf < 4; ++nf) {
          acc[mf][nf] = MFMA(ah[mf], bh[nf], acc[mf][nf]);
          acc[mf][nf] = MFMA(ah[mf], bl[nf], acc[mf][nf]);
          acc[mf][nf] = MFMA(al[mf], bh[nf], acc[mf][nf]);
        }
    }
    if (c < 7) {
      __syncthreads();
      STAGE_ALL((c + 1) * 64)
      __syncthreads();
    }
  }
#undef STAGE_ALL

#pragma unroll
  for (int mf = 0; mf < 4; ++mf)
#pragma unroll
    for (int nf = 0; nf < 4; ++nf) {
      const f32x4 a = acc[mf][nf];
      const int n = n0 + bR0 + nf * 16 + (lane & 15);
      const int mb = m0 + aR0 + mf * 16 + ((lane >> 4) << 2);
      ushort* p = C + (size_t)n * NP + mb;
      *(uint2*)p = make_uint2(pack_bf16(a.x, a.y), pack_bf16(a.z, a.w));
    }
}

// ---------------- zero sel + counters/flags ----------------
__global__ void k_zero(int* __restrict__ sel, unsigned* __restrict__ cnts) {
  int i = blockIdx.x * 256 + threadIdx.x;
  if (i < NROWS) sel[i] = 0;
  if (blockIdx.x == 0 && threadIdx.x < 128) cnts[threadIdx.x] = 0;
}

// ================= standalone A (prologue, t=0): gates + h,c; tail-16: b1 =================
__launch_bounds__(256)
__global__ void k_A(const float* __restrict__ attn_mem, const float* __restrict__ stoprow,
                    const float* __restrict__ init_i, const float* __restrict__ init_h,
                    const float* __restrict__ init_c,
                    const float* __restrict__ w_ih, const float* __restrict__ w_hh,
                    const float* __restrict__ b_ih, const float* __restrict__ b_hh,
                    const float* __restrict__ hop_wq,
                    float* __restrict__ hv0, float* __restrict__ hv1,
                    float* __restrict__ cv0, float* __restrict__ cv1,
                    float* __restrict__ b1, const int* __restrict__ xrow_buf,
                    unsigned* __restrict__ cntA, unsigned* __restrict__ flagA, int t) {
  __shared__ float g4[4];
  __shared__ float hs[512];
  __shared__ float red2[256];
  __shared__ int sOld;
  const int b = blockIdx.x, tid = threadIdx.x, w = tid >> 6, lane = tid & 63;
  const int xrow = (t == 0) ? -1 : ALD((int*)xrow_buf);
  const float* xp = (xrow < 0) ? init_i
                               : ((xrow == NITEMS) ? stoprow : attn_mem + (size_t)xrow * DD);
  const float* hsrc = (t == 0) ? init_h : ((t & 1) ? hv0 : hv1);
  float* hdst = (t & 1) ? hv1 : hv0;
  const float* csrc = (t == 0) ? init_c : ((t & 1) ? cv0 : cv1);
  float* cdst = (t & 1) ? cv1 : cv0;

  const int r = w * 512 + b;
  const float4* x4 = (const float4*)xp;
  const float4* h4 = (const float4*)hsrc;
  const float4* wi = (const float4*)(w_ih + (size_t)r * DD);
  const float4* wh = (const float4*)(w_hh + (size_t)r * DD);
  float s = 0.f;
  float4 a, ww;
  a = x4[lane * 2];     ww = wi[lane * 2];     s += a.x * ww.x + a.y * ww.y + a.z * ww.z + a.w * ww.w;
  a = x4[lane * 2 + 1]; ww = wi[lane * 2 + 1]; s += a.x * ww.x + a.y * ww.y + a.z * ww.z + a.w * ww.w;
  a = h4[lane * 2];     ww = wh[lane * 2];     s += a.x * ww.x + a.y * ww.y + a.z * ww.z + a.w * ww.w;
  a = h4[lane * 2 + 1]; ww = wh[lane * 2 + 1]; s += a.x * ww.x + a.y * ww.y + a.z * ww.z + a.w * ww.w;
#pragma unroll
  for (int off = 32; off > 0; off >>= 1) s += __shfl_xor(s, off);
  if (lane == 0) g4[w] = s + b_ih[r] + b_hh[r];
  __syncthreads();
  if (tid == 0) {
    const float si = 1.f / (1.f + expf(-g4[0]));
    const float sf = 1.f / (1.f + expf(-g4[1]));
    const float so = 1.f / (1.f + expf(-g4[3]));
    const float cn = sf * csrc[b] + si * tanhf(g4[2]);
    cdst[b] = cn;
    AST(&hdst[b], so * tanhf(cn));
  }
  __syncthreads();
  if (tid == 0) {
    unsigned old = AADD_REL(cntA);
    if (old == 511u) { FLAG_SET(flagA); AST(cntA, 0u); }
    sOld = (int)old;
  }
  __syncthreads();
  const int old = sOld;
  if (old >= 496) {
    if (tid == 0 && old != 511) {
      while (FLAG_GET(flagA) == 0u) __builtin_amdgcn_s_sleep(2);
    }
    __syncthreads();
    const int c0 = (old - 496) * 32;
    hs[tid] = ALD(&hdst[tid]);
    hs[tid + 256] = ALD(&hdst[tid + 256]);
    __syncthreads();
    const int col = c0 + (tid & 31), seg = tid >> 5;
    float acc = 0.f;
#pragma unroll 8
    for (int i = seg * 64; i < seg * 64 + 64; ++i)
      acc = fmaf(hs[i], hop_wq[(size_t)i * 512 + col], acc);
    red2[tid] = acc;
    __syncthreads();
    if (tid < 32) {
      float sm = 0.f;
#pragma unroll
      for (int g2 = 0; g2 < 8; ++g2) sm += red2[tid + 32 * g2];
      b1[c0 + tid] = sm;
    }
  }
}

// ================= k_step: one full decode step (B1 -> qn -> b2 -> C -> final -> A(t+1)) =================
struct SP {
  const ushort *hopT, *attnT;
  const float *b1v, *hop_v, *attn_wq, *attn_v, *gumbel;
  float *e, *bZ1, *qn, *b2, *bZa, *bsc;
  ull* bkey;
  int* sel;
  int *done_buf, *xrow_buf;
  float* outf;
  const float *attn_mem, *stoprow, *init_i, *init_h, *init_c;
  const float *w_ih, *w_hh, *b_ih, *b_hh, *hop_wq;
  float *hv0, *hv1, *cv0, *cv1, *b1out;
  unsigned* cnts;
  int t;
};

union SMu {
  struct { float spart[4][128]; float bias[512]; float vv[512]; } sw;
  struct { float red[256]; } r;
  struct { float rz[256]; ull rk[256]; float rs[256]; } fin;
  struct { float g4[4]; float hs[512]; float red2[256]; } pa;
};

__launch_bounds__(256)
__global__ void k_step(SP p) {
  __shared__ SMu sm;
  __shared__ int sOld;
  const int tid = threadIdx.x, b = blockIdx.x;
  const int w = tid >> 6, lane = tid & 63;
  const int t = p.t;
  unsigned* c1 = p.cnts + 0;
  unsigned* c2 = p.cnts + 1;
  unsigned* c2b = p.cnts + 2;
  unsigned* c3 = p.cnts + 3;
  unsigned* cA = p.cnts + 4;
  unsigned* f1 = p.cnts + 16 + t;
  unsigned* f2a = p.cnts + 32 + t;
  unsigned* f2 = p.cnts + 48 + t;
  unsigned* fF = p.cnts + 64 + t;
  unsigned* fA = p.cnts + 80 + t;

  // ======== Phase B1: hop scores (392 groups x 128 rows) ========
  for (int i = tid; i < 512; i += 256) {
    sm.sw.bias[i] = p.b1v[i];
    sm.sw.vv[i] = p.hop_v[i];
  }
  __syncthreads();
  if (b < 392) {
    const int mb = b * 128 + lane * 2;
    const int h0 = w * 128;
    const ushort* fp = p.hopT + (size_t)h0 * NP + mb;
    float a0 = 0.f, a1 = 0.f;
#pragma unroll 8
    for (int hh = 0; hh < 128; ++hh) {
      const unsigned u = *(const unsigned*)fp;
      fp += NP;
      const float bb = sm.sw.bias[h0 + hh], vv = sm.sw.vv[h0 + hh];
      a0 += ftanh(bflo(u) + bb) * vv;
      a1 += ftanh(bfhi(u) + bb) * vv;
    }
    sm.sw.spart[w][lane * 2] = a0;
    sm.sw.spart[w][lane * 2 + 1] = a1;
    __syncthreads();
    if (w < 2) {
      const int idx = w * 64 + lane;
      const int m = b * 128 + idx;
      float s = sm.sw.spart[0][idx] + sm.sw.spart[1][idx] + sm.sw.spart[2][idx] +
                sm.sw.spart[3][idx];
      float ev = (m < NROWS) ? fexp(s) : 0.f;
      p.e[m] = ev;
      float Z = ev;
#pragma unroll
      for (int off = 32; off > 0; off >>= 1) Z += __shfl_xor(Z, off);
      if (lane == 0) AST(&p.bZ1[b * 2 + w], Z);
    }
  }
  // -------- barrier 1 --------
  __syncthreads();
  if (tid == 0) {
    unsigned old = AADD_REL(c1);
    if (old == NSB - 1u) { FLAG_SET(f1); AST(c1, 0u); }
    else { while (FLAG_GET(f1) == 0u) __builtin_amdgcn_s_sleep(2); }
  }
  __syncthreads();

  // ======== Phase B2: qn'[b] = dot(e, hopT row b) (unnormalized) ========
  {
    const ushort* fr = p.hopT + (size_t)b * NP;
    float acc = 0.f;
#pragma unroll 4
    for (int m0 = tid * 8; m0 < NP; m0 += 2048) {
      const uint4 F = *(const uint4*)(fr + m0);
      const float4 e0 = *(const float4*)(p.e + m0);
      const float4 e1 = *(const float4*)(p.e + m0 + 4);
      acc += bflo(F.x) * e0.x + bfhi(F.x) * e0.y + bflo(F.y) * e0.z + bfhi(F.y) * e0.w +
             bflo(F.z) * e1.x + bfhi(F.z) * e1.y + bflo(F.w) * e1.z + bfhi(F.w) * e1.w;
    }
    sm.r.red[tid] = acc;
    __syncthreads();
    for (int s2 = 128; s2 > 0; s2 >>= 1) {
      if (tid < s2) sm.r.red[tid] += sm.r.red[tid + s2];
      __syncthreads();
    }
    if (tid == 0) AST(&p.qn[b], sm.r.red[0]);
  }
  // -------- barrier 2 + tail b2 --------
  __syncthreads();
  if (tid == 0) {
    unsigned old = AADD_REL(c2);
    sOld = (int)old;
    if (old == NSB - 1u) { FLAG_SET(f2a); AST(c2, 0u); }
    else if (old >= NSB - 8u) {
      while (FLAG_GET(f2a) == 0u) __builtin_amdgcn_s_sleep(2);
    }
  }
  __syncthreads();
  const int o2 = sOld;
  if (o2 >= NSB - 8) {
    // Zt
    float zl = 0.f;
    for (int i = tid; i < NGRP; i += 256) zl += ALD(&p.bZ1[i]);
    sm.r.red[tid] = zl;
    __syncthreads();
    for (int s2 = 128; s2 > 0; s2 >>= 1) {
      if (tid < s2) sm.r.red[tid] += sm.r.red[tid + s2];
      __syncthreads();
    }
    const float Zt = sm.r.red[0];
    __syncthreads();
    const int li = o2 - (NSB - 8);
    const int j = li * 64 + (tid & 63), is = tid >> 6;
    float a = 0.f;
#pragma unroll 8
    for (int i2 = is * 128; i2 < is * 128 + 128; ++i2)
      a = fmaf(ALD(&p.qn[i2]), p.attn_wq[(size_t)i2 * 512 + j], a);
    sm.r.red[tid] = a;
    __syncthreads();
    if (tid < 64)
      AST(&p.b2[li * 64 + tid],
          (sm.r.red[tid] + sm.r.red[tid + 64] + sm.r.red[tid + 128] + sm.r.red[tid + 192]) / Zt);
    __syncthreads();
    if (tid == 0) {
      unsigned ob = AADD_REL(c2b);
      if (ob == 7u) { FLAG_SET(f2); AST(c2b, 0u); }
    }
  }
  if (tid == 0) {
    while (FLAG_GET(f2) == 0u) __builtin_amdgcn_s_sleep(2);
  }
  __syncthreads();

  // ======== Phase C: attn scores + gumbel argmax (392 groups x 128 rows) ========
  for (int i = tid; i < 512; i += 256) {
    sm.sw.bias[i] = ALD(&p.b2[i]);
    sm.sw.vv[i] = p.attn_v[i];
  }
  __syncthreads();
  if (b < 392) {
    const int mb = b * 128 + lane * 2;
    const int h0 = w * 128;
    const ushort* fp = p.attnT + (size_t)h0 * NP + mb;
    float a0 = 0.f, a1 = 0.f;
#pragma unroll 8
    for (int hh = 0; hh < 128; ++hh) {
      const unsigned u = *(const unsigned*)fp;
      fp += NP;
      const float bb = sm.sw.bias[h0 + hh], vv = sm.sw.vv[h0 + hh];
      a0 += ftanh(bflo(u) + bb) * vv;
      a1 += ftanh(bfhi(u) + bb) * vv;
    }
    sm.sw.spart[w][lane * 2] = a0;
    sm.sw.spart[w][lane * 2 + 1] = a1;
    __syncthreads();
    if (w < 2) {
      const int idx = w * 64 + lane;
      const int m = b * 128 + idx;
      float s = sm.sw.spart[0][idx] + sm.sw.spart[1][idx] + sm.sw.spart[2][idx] +
                sm.sw.spart[3][idx];
      const bool valid = (m < NROWS);
      float Z, sv;
      ull key;
      if (valid) {
        const float se = p.sel[m] ? NEGV : s;
        sv = se;
        key = ((ull)fkey(se + p.gumbel[m]) << 32) | (unsigned)(NITEMS - m);
        Z = fexp(se);
      } else {
        key = 0;
        Z = 0.f;
        sv = 0.f;
      }
#pragma unroll
      for (int off = 32; off > 0; off >>= 1) {
        Z += __shfl_xor(Z, off);
        ull Ko = __shfl_xor(key, off);
        float so = __shfl_xor(sv, off);
        if (Ko > key) { key = Ko; sv = so; }
      }
      if (lane == 0) {
        AST(&p.bZa[b * 2 + w], Z);
        AST(&p.bkey[b * 2 + w], key);
        AST(&p.bsc[b * 2 + w], sv);
      }
    }
  }
  // -------- barrier 3 + final (by last arriver) --------
  __syncthreads();
  if (tid == 0) {
    unsigned old = AADD_REL(c3);
    sOld = (int)old;
    if (old == NSB - 1u) AST(c3, 0u);
  }
  __syncthreads();
  if (sOld == NSB - 1) {
    float Zl = 0.f, Sl = 0.f;
    ull Kl = 0;
    for (int i = tid; i < NGRP; i += 256) {
      Zl += ALD(&p.bZa[i]);
      ull k = ALD(&p.bkey[i]);
      if (k > Kl) { Kl = k; Sl = ALD(&p.bsc[i]); }
    }
    sm.fin.rz[tid] = Zl;
    sm.fin.rk[tid] = Kl;
    sm.fin.rs[tid] = Sl;
    __syncthreads();
    for (int s2 = 128; s2 > 0; s2 >>= 1) {
      if (tid < s2) {
        sm.fin.rz[tid] += sm.fin.rz[tid + s2];
        if (sm.fin.rk[tid + s2] > sm.fin.rk[tid]) {
          sm.fin.rk[tid] = sm.fin.rk[tid + s2];
          sm.fin.rs[tid] = sm.fin.rs[tid + s2];
        }
      }
      __syncthreads();
    }
    if (tid == 0) {
      const float Z = sm.fin.rz[0];
      const ull K = sm.fin.rk[0];
      const int out = NITEMS - (int)(unsigned)(K & 0xffffffffull);
      const int d_in = (t == 0) ? 0 : ALD(p.done_buf);
      const int xprev = (t == 0) ? -1 : ALD(p.xrow_buf);
      const int nd = d_in | (out == NITEMS);
      p.outf[t] = (float)(d_in ? NITEMS : out);
      p.outf[TT + t] = d_in ? 0.f : (sm.fin.rs[0] - logf(Z));
      if (!d_in) p.sel[out] = 1;
      AST(p.done_buf, nd);
      AST(p.xrow_buf, nd ? xprev : out);
      FLAG_SET(fF);
    }
  }
  if (tid == 0) {
    while (FLAG_GET(fF) == 0u) __builtin_amdgcn_s_sleep(2);
  }
  __syncthreads();

  // ======== Phase A: LSTM for step t+1 ========
  {
    const int tA = t + 1;
    const int xrow = ALD(p.xrow_buf);
    const float* xp = (xrow < 0) ? p.init_i
                                 : ((xrow == NITEMS) ? p.stoprow : p.attn_mem + (size_t)xrow * DD);
    const float* hsrc = (tA & 1) ? p.hv0 : p.hv1;
    float* hdst = (tA & 1) ? p.hv1 : p.hv0;
    const float* csrc = (tA & 1) ? p.cv0 : p.cv1;
    float* cdst = (tA & 1) ? p.cv1 : p.cv0;

    const int r = w * 512 + b;
    const float4* x4 = (const float4*)xp;
    const float4* h4 = (const float4*)hsrc;
    const float4* wi = (const float4*)(p.w_ih + (size_t)r * DD);
    const float4* wh = (const float4*)(p.w_hh + (size_t)r * DD);
    float s = 0.f;
    float4 a, ww;
    a = x4[lane * 2];     ww = wi[lane * 2];     s += a.x * ww.x + a.y * ww.y + a.z * ww.z + a.w * ww.w;
    a = x4[lane * 2 + 1]; ww = wi[lane * 2 + 1]; s += a.x * ww.x + a.y * ww.y + a.z * ww.z + a.w * ww.w;
    a = h4[lane * 2];     ww = wh[lane * 2];     s += a.x * ww.x + a.y * ww.y + a.z * ww.z + a.w * ww.w;
    a = h4[lane * 2 + 1]; ww = wh[lane * 2 + 1]; s += a.x * ww.x + a.y * ww.y + a.z * ww.z + a.w * ww.w;
#pragma unroll
    for (int off = 32; off > 0; off >>= 1) s += __shfl_xor(s, off);
    if (lane == 0) sm.pa.g4[w] = s + p.b_ih[r] + p.b_hh[r];
    __syncthreads();
    if (tid == 0) {
      const float si = 1.f / (1.f + expf(-sm.pa.g4[0]));
      const float sf = 1.f / (1.f + expf(-sm.pa.g4[1]));
      const float so = 1.f / (1.f + expf(-sm.pa.g4[3]));
      const float cn = sf * csrc[b] + si * tanhf(sm.pa.g4[2]);
      cdst[b] = cn;
      AST(&hdst[b], so * tanhf(cn));
    }
    __syncthreads();
    if (tid == 0) {
      unsigned old = AADD_REL(cA);
      if (old == NSB - 1u) { FLAG_SET(fA); AST(cA, 0u); }
      sOld = (int)old;
    }
    __syncthreads();
    const int old = sOld;
    if (old >= NSB - 16) {
      if (tid == 0 && old != NSB - 1) {
        while (FLAG_GET(fA) == 0u) __builtin_amdgcn_s_sleep(2);
      }
      __syncthreads();
      const int c0 = (old - (NSB - 16)) * 32;
      sm.pa.hs[tid] = ALD(&hdst[tid]);
      sm.pa.hs[tid + 256] = ALD(&hdst[tid + 256]);
      __syncthreads();
      const int col = c0 + (tid & 31), seg = tid >> 5;
      float acc = 0.f;
#pragma unroll 8
      for (int i = seg * 64; i < seg * 64 + 64; ++i)
        acc = fmaf(sm.pa.hs[i], p.hop_wq[(size_t)i * 512 + col], acc);
      sm.pa.red2[tid] = acc;
      __syncthreads();
      if (tid < 32) {
        float s2 = 0.f;
#pragma unroll
        for (int g2 = 0; g2 < 8; ++g2) s2 += sm.pa.red2[tid + 32 * g2];
        p.b1out[c0 + tid] = s2;
      }
    }
  }
}

// ======================================================================
extern "C" void kernel_launch(void* const* d_in, const int* in_sizes, int n_in,
                              void* d_out, int out_size, void* d_ws, size_t ws_size,
                              hipStream_t stream) {
  const float* attn_mem = (const float*)d_in[0];
  const float* stoprow  = (const float*)d_in[1];
  const float* init_h   = (const float*)d_in[2];
  const float* init_c   = (const float*)d_in[3];
  const float* init_i   = (const float*)d_in[4];
  const float* attn_wm  = (const float*)d_in[5];
  const float* attn_wq  = (const float*)d_in[6];
  const float* attn_v   = (const float*)d_in[7];
  const float* hop_wm   = (const float*)d_in[8];
  const float* hop_wq   = (const float*)d_in[9];
  const float* hop_v    = (const float*)d_in[10];
  const float* w_ih     = (const float*)d_in[11];
  const float* w_hh     = (const float*)d_in[12];
  const float* b_ih     = (const float*)d_in[13];
  const float* b_hh     = (const float*)d_in[14];
  const float* gumbel   = (const float*)d_in[15];

  float* ws = (float*)d_ws;
  size_t fo = 0;
  const size_t FB = (size_t)NP * 512 / 2;
  ushort* hop_featT  = (ushort*)(ws + fo); fo += FB;
  ushort* attn_featT = (ushort*)(ws + fo); fo += FB;
  ushort* Ahi = (ushort*)(ws + fo); fo += FB;
  ushort* Alo = (ushort*)(ws + fo); fo += FB;
  ushort* WhiT_a = (ushort*)(ws + fo); fo += 131072;
  ushort* WloT_a = (ushort*)(ws + fo); fo += 131072;
  ushort* WhiT_h = (ushort*)(ws + fo); fo += 131072;
  ushort* WloT_h = (ushort*)(ws + fo); fo += 131072;
  int* sel   = (int*)(ws + fo); fo += NP;
  float* e   = ws + fo; fo += NP;
  float* bZ1 = ws + fo; fo += 1024;
  float* bZa = ws + fo; fo += 1024;
  float* bsc = ws + fo; fo += 1024;
  ull* bkey  = (ull*)(ws + fo); fo += 2048;
  float* hv0 = ws + fo; fo += HH;
  float* hv1 = ws + fo; fo += HH;
  float* cv0 = ws + fo; fo += HH;
  float* cv1 = ws + fo; fo += HH;
  float* b1  = ws + fo; fo += HH;
  float* b2  = ws + fo; fo += HH;
  float* qn  = ws + fo; fo += HH;
  unsigned* cnts = (unsigned*)(ws + fo); fo += 128;
  int* done_buf = (int*)(ws + fo); fo += 2;
  int* xrow_buf = (int*)(ws + fo); fo += 2;
  if (fo * sizeof(float) > ws_size) return;

  float* outf = (float*)d_out;

  k_zero<<<NP / 256, 256, 0, stream>>>(sel, cnts);
  k_convA<<<(NP * 512 / 8) / 256, 256, 0, stream>>>(attn_mem, stoprow, Ahi, Alo);
  k_convBT<<<512, 256, 0, stream>>>(attn_wm, WhiT_a, WloT_a);
  k_convBT<<<512, 256, 0, stream>>>(hop_wm, WhiT_h, WloT_h);

  dim3 ggrid(4, NP / 128);  // 1568 blocks = 8*196
  k_mfma<<<ggrid, 256, 0, stream>>>(Ahi, Alo, WhiT_a, WloT_a, attn_featT);
  k_mfma<<<ggrid, 256, 0, stream>>>(Ahi, Alo, WhiT_h, WloT_h, hop_featT);

  // prologue: A(0)
  k_A<<<NSB, 256, 0, stream>>>(attn_mem, stoprow, init_i, init_h, init_c,
                               w_ih, w_hh, b_ih, b_hh, hop_wq,
                               hv0, hv1, cv0, cv1, b1, xrow_buf,
                               cnts + 5, cnts + 96, 0);

  SP p;
  p.hopT = hop_featT; p.attnT = attn_featT;
  p.b1v = b1; p.hop_v = hop_v; p.attn_wq = attn_wq; p.attn_v = attn_v;
  p.e = e; p.bZ1 = bZ1; p.qn = qn; p.b2 = b2;
  p.bZa = bZa; p.bsc = bsc; p.bkey = bkey;
  p.sel = sel; p.done_buf = done_buf; p.xrow_buf = xrow_buf; p.outf = outf;
  p.attn_mem = attn_mem; p.stoprow = stoprow;
  p.init_i = init_i; p.init_h = init_h; p.init_c = init_c;
  p.w_ih = w_ih; p.w_hh = w_hh; p.b_ih = b_ih; p.b_hh = b_hh; p.hop_wq = hop_wq;
  p.hv0 = hv0; p.hv1 = hv1; p.cv0 = cv0; p.cv1 = cv1; p.b1out = b1;
  p.cnts = cnts;

  for (int t = 0; t < TT; ++t) {
    p.gumbel = gumbel + (size_t)t * NROWS;
    p.t = t;
    k_step<<<NSB, 256, 0, stream>>>(p);
  }
}

// Round 18
// 1627.492 us; speedup vs baseline: 2.7705x; 2.7705x over previous
//
#include <hip/hip_runtime.h>
#include <math.h>

#define NITEMS 50000
#define NROWS 50001
#define NP 50176          // padded row count (392*128 = 196*256)
#define DD 512
#define HH 512
#define TT 16
#define NEGV (-1e18f)
#define NGRP 784          // 196 blocks x 4 partials
#define NGC 196           // transposed-sweep blocks (256 rows each)

typedef unsigned long long ull;
typedef unsigned short ushort;
typedef short short8 __attribute__((ext_vector_type(8)));
typedef float f32x4 __attribute__((ext_vector_type(4)));

// ---- scoped-atomic helpers (agent scope) ----
#define AST(p, v) __hip_atomic_store((p), (v), __ATOMIC_RELAXED, __HIP_MEMORY_SCOPE_AGENT)
#define ALD(p) __hip_atomic_load((p), __ATOMIC_RELAXED, __HIP_MEMORY_SCOPE_AGENT)
#define AADD_REL(p) __hip_atomic_fetch_add((p), 1u, __ATOMIC_ACQ_REL, __HIP_MEMORY_SCOPE_AGENT)
#define FLAG_SET(p) __hip_atomic_store((p), 1u, __ATOMIC_RELEASE, __HIP_MEMORY_SCOPE_AGENT)
#define FLAG_GET(p) __hip_atomic_load((p), __ATOMIC_ACQUIRE, __HIP_MEMORY_SCOPE_AGENT)

__device__ __forceinline__ unsigned fkey(float f) {
  unsigned u = __float_as_uint(f);
  return (u & 0x80000000u) ? ~u : (u | 0x80000000u);
}
__device__ __forceinline__ float ftanh(float x) {
  float e = __builtin_amdgcn_exp2f(x * 2.885390081777927f);
  return 1.f - 2.f * __builtin_amdgcn_rcpf(e + 1.f);
}
__device__ __forceinline__ float fexp(float x) {
  return __builtin_amdgcn_exp2f(x * 1.4426950408889634f);
}
__device__ __forceinline__ ushort rne1(float a) {
  unsigned u = __float_as_uint(a);
  return (ushort)((u + 0x7fffu + ((u >> 16) & 1u)) >> 16);
}
__device__ __forceinline__ float bf2f(ushort h) { return __uint_as_float((unsigned)h << 16); }
__device__ __forceinline__ unsigned pack_bf16(float a, float b) {
  return (unsigned)rne1(a) | ((unsigned)rne1(b) << 16);
}
__device__ __forceinline__ float bflo(unsigned u) { return __uint_as_float(u << 16); }
__device__ __forceinline__ float bfhi(unsigned u) { return __uint_as_float(u & 0xffff0000u); }

__device__ __forceinline__ void gl_lds16(const void* g, void* l) {
#if __has_builtin(__builtin_amdgcn_global_load_lds)
  __builtin_amdgcn_global_load_lds((const __attribute__((address_space(1))) unsigned*)g,
                                   (__attribute__((address_space(3))) unsigned*)l, 16, 0, 0);
#else
  const int lane = threadIdx.x & 63;
  *(uint4*)((char*)l + lane * 16) = *(const uint4*)g;
#endif
}

#define MFMA(a, b, c) __builtin_amdgcn_mfma_f32_16x16x32_bf16(a, b, c, 0, 0, 0)

// ---------------- A -> (Ahi, Alo) bf16 [NP][512]; also zeros sel + counters ----------------
__global__ void k_convA(const float* __restrict__ A0, const float* __restrict__ stoprow,
                        ushort* __restrict__ Ahi, ushort* __restrict__ Alo,
                        int* __restrict__ sel, unsigned* __restrict__ cnts) {
  const size_t t = (size_t)blockIdx.x * 256 + threadIdx.x;
  // fold in: zero sel + counters (NP*512/8/256 = 12544 blocks; first 196 cover sel)
  if (blockIdx.x < 196) {
    int i = blockIdx.x * 256 + threadIdx.x;
    if (i < NROWS) sel[i] = 0;
    if (blockIdx.x == 0 && threadIdx.x < 128) cnts[threadIdx.x] = 0;
  }
  const size_t base = t * 8;
  const int row = (int)(base >> 9);
  float v[8];
  if (row < NITEMS) {
    const float4* p = (const float4*)(A0 + base);
    float4 x = p[0], y = p[1];
    v[0] = x.x; v[1] = x.y; v[2] = x.z; v[3] = x.w;
    v[4] = y.x; v[5] = y.y; v[6] = y.z; v[7] = y.w;
  } else if (row == NITEMS) {
    const float4* p = (const float4*)(stoprow + (base & 511));
    float4 x = p[0], y = p[1];
    v[0] = x.x; v[1] = x.y; v[2] = x.z; v[3] = x.w;
    v[4] = y.x; v[5] = y.y; v[6] = y.z; v[7] = y.w;
  } else {
#pragma unroll
    for (int j = 0; j < 8; ++j) v[j] = 0.f;
  }
  unsigned hw[4], lw[4];
#pragma unroll
  for (int j = 0; j < 4; ++j) {
    float a0 = v[2 * j], a1 = v[2 * j + 1];
    ushort h0 = rne1(a0), h1 = rne1(a1);
    hw[j] = (unsigned)h0 | ((unsigned)h1 << 16);
    lw[j] = pack_bf16(a0 - bf2f(h0), a1 - bf2f(h1));
  }
  *(uint4*)(Ahi + base) = make_uint4(hw[0], hw[1], hw[2], hw[3]);
  *(uint4*)(Alo + base) = make_uint4(lw[0], lw[1], lw[2], lw[3]);
}

// ---------------- both W [k][n] -> transposed bf16 in one launch (1024 blocks) ----------------
__global__ void k_convBT2(const float* __restrict__ Wa, const float* __restrict__ Wh,
                          ushort* __restrict__ WhiT_a, ushort* __restrict__ WloT_a,
                          ushort* __restrict__ WhiT_h, ushort* __restrict__ WloT_h) {
  const int n = blockIdx.x & 511;
  const float* W = (blockIdx.x < 512) ? Wa : Wh;
  ushort* Whi = (blockIdx.x < 512) ? WhiT_a : WhiT_h;
  ushort* Wlo = (blockIdx.x < 512) ? WloT_a : WloT_h;
  const int k0 = threadIdx.x * 2;
  float a0 = W[(size_t)k0 * 512 + n];
  float a1 = W[(size_t)(k0 + 1) * 512 + n];
  ushort h0 = rne1(a0), h1 = rne1(a1);
  *(unsigned*)(Whi + (size_t)n * 512 + k0) = (unsigned)h0 | ((unsigned)h1 << 16);
  *(unsigned*)(Wlo + (size_t)n * 512 + k0) = pack_bf16(a0 - bf2f(h0), a1 - bf2f(h1));
}

// ---------------- MFMA GEMM (verified R10; swizzle exact: 1568 = 8*196) ----------------
__launch_bounds__(256, 2)
__global__ void k_mfma(const ushort* __restrict__ Ahi, const ushort* __restrict__ Alo,
                       const ushort* __restrict__ BhT, const ushort* __restrict__ BlT,
                       ushort* __restrict__ C) {
  __shared__ __align__(16) char lds[65536];
  char* sA0 = lds;
  char* sA1 = lds + 16384;
  char* sB0 = lds + 32768;
  char* sB1 = lds + 49152;
  const int tid = threadIdx.x;
  const int lane = tid & 63, w = tid >> 6;
  const int lid = blockIdx.y * 4 + blockIdx.x;
  const int xcd = lid & 7, pos = lid >> 3;
  const int orig = xcd * 196 + pos;
  const int m0 = (orig >> 2) * 128, n0 = (orig & 3) * 128;
  const int aR0 = (w & 1) * 64, bR0 = (w >> 1) * 64;

  f32x4 acc[4][4];
  const f32x4 z4 = {0.f, 0.f, 0.f, 0.f};
#pragma unroll
  for (int i = 0; i < 4; ++i)
#pragma unroll
    for (int j = 0; j < 4; ++j) acc[i][j] = z4;

#define STAGE_ALL(KT)                                                                     \
  {                                                                                       \
    _Pragma("unroll") for (int i = 0; i < 4; ++i) {                                       \
      const int row = i * 32 + (tid >> 3);                                                \
      const int kb = ((tid & 7) << 4) ^ ((row & 7) << 4);                                 \
      const int ldso = i * 4096 + (w << 10);                                              \
      gl_lds16((const char*)(Ahi + ((size_t)(m0 + row) << 9) + (KT)) + kb, sA0 + ldso);   \
      gl_lds16((const char*)(Alo + ((size_t)(m0 + row) << 9) + (KT)) + kb, sA1 + ldso);   \
      gl_lds16((const char*)(BhT + ((size_t)(n0 + row) << 9) + (KT)) + kb, sB0 + ldso);   \
      gl_lds16((const char*)(BlT + ((size_t)(n0 + row) << 9) + (KT)) + kb, sB1 + ldso);   \
    }                                                                                     \
  }

  STAGE_ALL(0)
  __syncthreads();
  for (int c = 0; c < 8; ++c) {
#pragma unroll
    for (int ks = 0; ks < 2; ++ks) {
      short8 ah[4], al[4], bh[4], bl[4];
      const int kbb = ks * 64 + ((lane >> 4) << 4);
#pragma unroll
      for (int f = 0; f < 4; ++f) {
        const int ra = aR0 + f * 16 + (lane & 15);
        const int oa = ra * 128 + (kbb ^ ((ra & 7) << 4));
        ah[f] = *(const short8*)(sA0 + oa);
        al[f] = *(const short8*)(sA1 + oa);
        const int rb = bR0 + f * 16 + (lane & 15);
        const int ob = rb * 128 + (kbb ^ ((rb & 7) << 4));
        bh[f] = *(const short8*)(sB0 + ob);
        bl[f] = *(const short8*)(sB1 + ob);
      }
#pragma unroll
      for (int mf = 0; mf < 4; ++mf)
#pragma unroll
        for (int nf = 0; nf < 4; ++nf) {
          acc[mf][nf] = MFMA(ah[mf], bh[nf], acc[mf][nf]);
          acc[mf][nf] = MFMA(ah[mf], bl[nf], acc[mf][nf]);
          acc[mf][nf] = MFMA(al[mf], bh[nf], acc[mf][nf]);
        }
    }
    if (c < 7) {
      __syncthreads();
      STAGE_ALL((c + 1) * 64)
      __syncthreads();
    }
  }
#undef STAGE_ALL

#pragma unroll
  for (int mf = 0; mf < 4; ++mf)
#pragma unroll
    for (int nf = 0; nf < 4; ++nf) {
      const f32x4 a = acc[mf][nf];
      const int n = n0 + bR0 + nf * 16 + (lane & 15);
      const int mb = m0 + aR0 + mf * 16 + ((lane >> 4) << 2);
      ushort* p = C + (size_t)n * NP + mb;
      *(uint2*)p = make_uint2(pack_bf16(a.x, a.y), pack_bf16(a.z, a.w));
    }
}

// ================= A: LSTM gates + h,c; last-16 blocks: b1 slices =================
__launch_bounds__(256)
__global__ void k_A(const float* __restrict__ attn_mem, const float* __restrict__ stoprow,
                    const float* __restrict__ init_i, const float* __restrict__ init_h,
                    const float* __restrict__ init_c,
                    const float* __restrict__ w_ih, const float* __restrict__ w_hh,
                    const float* __restrict__ b_ih, const float* __restrict__ b_hh,
                    const float* __restrict__ hop_wq,
                    float* __restrict__ hv0, float* __restrict__ hv1,
                    float* __restrict__ cv0, float* __restrict__ cv1,
                    float* __restrict__ b1, const int* __restrict__ xrow_buf,
                    unsigned* __restrict__ cntA, unsigned* __restrict__ flagA, int t) {
  __shared__ float g4[4];
  __shared__ float hs[512];
  __shared__ float red2[256];
  __shared__ int sOld;
  const int b = blockIdx.x, tid = threadIdx.x, w = tid >> 6, lane = tid & 63;
  const int xrow = (t == 0) ? -1 : ALD((int*)xrow_buf);
  const float* xp = (xrow < 0) ? init_i
                               : ((xrow == NITEMS) ? stoprow : attn_mem + (size_t)xrow * DD);
  const float* hsrc = (t == 0) ? init_h : ((t & 1) ? hv0 : hv1);
  float* hdst = (t & 1) ? hv1 : hv0;
  const float* csrc = (t == 0) ? init_c : ((t & 1) ? cv0 : cv1);
  float* cdst = (t & 1) ? cv1 : cv0;

  const int r = w * 512 + b;  // gate section w, unit b
  const float4* x4 = (const float4*)xp;
  const float4* h4 = (const float4*)hsrc;
  const float4* wi = (const float4*)(w_ih + (size_t)r * DD);
  const float4* wh = (const float4*)(w_hh + (size_t)r * DD);
  float s = 0.f;
  float4 a, ww;
  a = x4[lane * 2];     ww = wi[lane * 2];     s += a.x * ww.x + a.y * ww.y + a.z * ww.z + a.w * ww.w;
  a = x4[lane * 2 + 1]; ww = wi[lane * 2 + 1]; s += a.x * ww.x + a.y * ww.y + a.z * ww.z + a.w * ww.w;
  a = h4[lane * 2];     ww = wh[lane * 2];     s += a.x * ww.x + a.y * ww.y + a.z * ww.z + a.w * ww.w;
  a = h4[lane * 2 + 1]; ww = wh[lane * 2 + 1]; s += a.x * ww.x + a.y * ww.y + a.z * ww.z + a.w * ww.w;
#pragma unroll
  for (int off = 32; off > 0; off >>= 1) s += __shfl_xor(s, off);
  if (lane == 0) g4[w] = s + b_ih[r] + b_hh[r];
  __syncthreads();
  if (tid == 0) {
    const float si = 1.f / (1.f + expf(-g4[0]));
    const float sf = 1.f / (1.f + expf(-g4[1]));
    const float so = 1.f / (1.f + expf(-g4[3]));
    const float cn = sf * csrc[b] + si * tanhf(g4[2]);
    cdst[b] = cn;
    AST(&hdst[b], so * tanhf(cn));
  }
  __syncthreads();
  if (tid == 0) {
    unsigned old = AADD_REL(cntA);
    if (old == 511u) { FLAG_SET(flagA); AST(cntA, 0u); }
    sOld = (int)old;
  }
  __syncthreads();
  const int old = sOld;
  if (old >= 496) {
    if (tid == 0 && old != 511) {
      while (FLAG_GET(flagA) == 0u) __builtin_amdgcn_s_sleep(2);
    }
    __syncthreads();
    const int c0 = (old - 496) * 32;
    hs[tid] = ALD(&hdst[tid]);
    hs[tid + 256] = ALD(&hdst[tid + 256]);
    __syncthreads();
    const int col = c0 + (tid & 31), seg = tid >> 5;
    float acc = 0.f;
#pragma unroll 8
    for (int i = seg * 64; i < seg * 64 + 64; ++i)
      acc = fmaf(hs[i], hop_wq[(size_t)i * 512 + col], acc);
    red2[tid] = acc;
    __syncthreads();
    if (tid < 32) {
      float sm = 0.f;
#pragma unroll
      for (int g2 = 0; g2 < 8; ++g2) sm += red2[tid + 32 * g2];
      b1[c0 + tid] = sm;
    }
  }
}

// ================= B1: hop scores (transposed sweep) -> e[m], Zt =================
__launch_bounds__(512)
__global__ void k_B1(const ushort* __restrict__ featT, const float* __restrict__ b1v,
                     const float* __restrict__ hv, float* __restrict__ e,
                     float* __restrict__ bZ1, float* __restrict__ Zt,
                     unsigned* __restrict__ cntB1) {
  __shared__ float spart[8][256];
  __shared__ float rz[512];
  __shared__ int isLast;
  const int tid = threadIdx.x, g = blockIdx.x;
  const int w = tid >> 6, lane = tid & 63;
  const int mb = g * 256 + lane * 4;
  const int h0 = w * 64;
  const ushort* fp = featT + (size_t)h0 * NP + mb;
  float a0 = 0.f, a1 = 0.f, a2 = 0.f, a3 = 0.f;
#pragma unroll 8
  for (int hh = 0; hh < 64; ++hh) {
    const uint2 u = *(const uint2*)fp;
    fp += NP;
    const float bb = b1v[h0 + hh], vv = hv[h0 + hh];
    a0 += ftanh(bflo(u.x) + bb) * vv;
    a1 += ftanh(bfhi(u.x) + bb) * vv;
    a2 += ftanh(bflo(u.y) + bb) * vv;
    a3 += ftanh(bfhi(u.y) + bb) * vv;
  }
  spart[w][lane * 4 + 0] = a0;
  spart[w][lane * 4 + 1] = a1;
  spart[w][lane * 4 + 2] = a2;
  spart[w][lane * 4 + 3] = a3;
  __syncthreads();
  if (w < 4) {
    const int idx = w * 64 + lane;
    const int m = g * 256 + idx;
    float s = 0.f;
#pragma unroll
    for (int w2 = 0; w2 < 8; ++w2) s += spart[w2][idx];
    float ev = (m < NROWS) ? fexp(s) : 0.f;
    e[m] = ev;
    float Z = ev;
#pragma unroll
    for (int off = 32; off > 0; off >>= 1) Z += __shfl_xor(Z, off);
    if (lane == 0) AST(&bZ1[g * 4 + w], Z);
  }
  __syncthreads();
  if (tid == 0) {
    unsigned old = AADD_REL(cntB1);
    isLast = (old == gridDim.x - 1);
    if (isLast) AST(cntB1, 0u);
  }
  __syncthreads();
  if (isLast) {
    float Zl = 0.f;
    for (int i = tid; i < NGRP; i += 512) Zl += ALD(&bZ1[i]);
    rz[tid] = Zl;
    __syncthreads();
    for (int s2 = 256; s2 > 0; s2 >>= 1) {
      if (tid < s2) rz[tid] += rz[tid + s2];
      __syncthreads();
    }
    if (tid == 0) *Zt = rz[0];
  }
}

// ================= B2: qn[h] = (e . featT[h]) / Zt ; last-8 blocks: b2 slices =================
__launch_bounds__(256)
__global__ void k_B2(const ushort* __restrict__ featT, const float* __restrict__ e,
                     const float* __restrict__ Zt, const float* __restrict__ attn_wq,
                     float* __restrict__ qn, float* __restrict__ b2,
                     unsigned* __restrict__ cntB2, unsigned* __restrict__ flagB2) {
  __shared__ float red[256];
  __shared__ int sOld;
  const int tid = threadIdx.x, h = blockIdx.x;
  const ushort* fr = featT + (size_t)h * NP;
  float acc = 0.f;
#pragma unroll 4
  for (int m0 = tid * 8; m0 < NP; m0 += 2048) {
    const uint4 F = *(const uint4*)(fr + m0);
    const float4 e0 = *(const float4*)(e + m0);
    const float4 e1 = *(const float4*)(e + m0 + 4);
    acc += bflo(F.x) * e0.x + bfhi(F.x) * e0.y + bflo(F.y) * e0.z + bfhi(F.y) * e0.w +
           bflo(F.z) * e1.x + bfhi(F.z) * e1.y + bflo(F.w) * e1.z + bfhi(F.w) * e1.w;
  }
  red[tid] = acc;
  __syncthreads();
  for (int s2 = 128; s2 > 0; s2 >>= 1) {
    if (tid < s2) red[tid] += red[tid + s2];
    __syncthreads();
  }
  if (tid == 0) AST(&qn[h], red[0] / (*Zt));
  __syncthreads();
  if (tid == 0) {
    unsigned old = AADD_REL(cntB2);
    if (old == 511u) { FLAG_SET(flagB2); AST(cntB2, 0u); }
    sOld = (int)old;
  }
  __syncthreads();
  const int old = sOld;
  if (old >= 504) {
    const int li = old - 504;
    if (tid == 0 && old != 511) {
      while (FLAG_GET(flagB2) == 0u) __builtin_amdgcn_s_sleep(2);
    }
    __syncthreads();
    const int j = li * 64 + (tid & 63), is = tid >> 6;
    float a = 0.f;
#pragma unroll 8
    for (int i2 = is * 128; i2 < is * 128 + 128; ++i2)
      a = fmaf(ALD(&qn[i2]), attn_wq[(size_t)i2 * 512 + j], a);
    red[tid] = a;
    __syncthreads();
    if (tid < 64) b2[li * 64 + tid] = red[tid] + red[tid + 64] + red[tid + 128] + red[tid + 192];
  }
}

// ================= C: attn transposed sweep; score carried with key; last block: sample =================
__launch_bounds__(512)
__global__ void k_C(const ushort* __restrict__ featT, const float* __restrict__ b2,
                    const float* __restrict__ av, int* __restrict__ sel,
                    const float* __restrict__ gum,
                    float* __restrict__ bZa, ull* __restrict__ bkey, float* __restrict__ bsc,
                    int* __restrict__ done_buf, int* __restrict__ xrow_buf,
                    float* __restrict__ outf, unsigned* __restrict__ cntC, int t) {
  __shared__ float spart[8][256];
  __shared__ float rz[512];
  __shared__ ull rk[512];
  __shared__ float rs[512];
  __shared__ int isLast;
  const int tid = threadIdx.x, g = blockIdx.x;
  const int w = tid >> 6, lane = tid & 63;
  const int mb = g * 256 + lane * 4;
  const int h0 = w * 64;
  const ushort* fp = featT + (size_t)h0 * NP + mb;
  float a0 = 0.f, a1 = 0.f, a2 = 0.f, a3 = 0.f;
#pragma unroll 8
  for (int hh = 0; hh < 64; ++hh) {
    const uint2 u = *(const uint2*)fp;
    fp += NP;
    const float bb = b2[h0 + hh], vv = av[h0 + hh];
    a0 += ftanh(bflo(u.x) + bb) * vv;
    a1 += ftanh(bfhi(u.x) + bb) * vv;
    a2 += ftanh(bflo(u.y) + bb) * vv;
    a3 += ftanh(bfhi(u.y) + bb) * vv;
  }
  spart[w][lane * 4 + 0] = a0;
  spart[w][lane * 4 + 1] = a1;
  spart[w][lane * 4 + 2] = a2;
  spart[w][lane * 4 + 3] = a3;
  __syncthreads();
  if (w < 4) {
    const int idx = w * 64 + lane;
    const int m = g * 256 + idx;
    float s = 0.f;
#pragma unroll
    for (int w2 = 0; w2 < 8; ++w2) s += spart[w2][idx];
    const bool valid = (m < NROWS);
    float Z, sv;
    ull key;
    if (valid) {
      const float se = sel[m] ? NEGV : s;
      sv = se;
      key = ((ull)fkey(se + gum[m]) << 32) | (unsigned)(NITEMS - m);
      Z = fexp(se);
    } else {
      key = 0;
      Z = 0.f;
      sv = 0.f;
    }
#pragma unroll
    for (int off = 32; off > 0; off >>= 1) {
      Z += __shfl_xor(Z, off);
      ull Ko = __shfl_xor(key, off);
      float so = __shfl_xor(sv, off);
      if (Ko > key) { key = Ko; sv = so; }
    }
    if (lane == 0) {
      AST(&bZa[g * 4 + w], Z);
      AST(&bkey[g * 4 + w], key);
      AST(&bsc[g * 4 + w], sv);
    }
  }
  __syncthreads();
  if (tid == 0) {
    unsigned old = AADD_REL(cntC);
    isLast = (old == gridDim.x - 1);
    if (isLast) AST(cntC, 0u);
  }
  __syncthreads();
  if (isLast) {
    float Zl = 0.f, Sl = 0.f;
    ull Kl = 0;
    for (int i = tid; i < NGRP; i += 512) {
      Zl += ALD(&bZa[i]);
      ull k = ALD(&bkey[i]);
      if (k > Kl) { Kl = k; Sl = ALD(&bsc[i]); }
    }
    rz[tid] = Zl;
    rk[tid] = Kl;
    rs[tid] = Sl;
    __syncthreads();
    for (int s2 = 256; s2 > 0; s2 >>= 1) {
      if (tid < s2) {
        rz[tid] += rz[tid + s2];
        if (rk[tid + s2] > rk[tid]) { rk[tid] = rk[tid + s2]; rs[tid] = rs[tid + s2]; }
      }
      __syncthreads();
    }
    if (tid == 0) {
      const float Z = rz[0];
      const ull K = rk[0];
      const int out = NITEMS - (int)(unsigned)(K & 0xffffffffull);
      const int d_in = (t == 0) ? 0 : *done_buf;
      const int xprev = (t == 0) ? -1 : *xrow_buf;
      const int nd = d_in | (out == NITEMS);
      outf[t] = (float)(d_in ? NITEMS : out);
      outf[TT + t] = d_in ? 0.f : (rs[0] - logf(Z));
      if (!d_in) sel[out] = 1;
      *done_buf = nd;
      *xrow_buf = nd ? xprev : out;
    }
  }
}

// ======================================================================
extern "C" void kernel_launch(void* const* d_in, const int* in_sizes, int n_in,
                              void* d_out, int out_size, void* d_ws, size_t ws_size,
                              hipStream_t stream) {
  const float* attn_mem = (const float*)d_in[0];
  const float* stoprow  = (const float*)d_in[1];
  const float* init_h   = (const float*)d_in[2];
  const float* init_c   = (const float*)d_in[3];
  const float* init_i   = (const float*)d_in[4];
  const float* attn_wm  = (const float*)d_in[5];
  const float* attn_wq  = (const float*)d_in[6];
  const float* attn_v   = (const float*)d_in[7];
  const float* hop_wm   = (const float*)d_in[8];
  const float* hop_wq   = (const float*)d_in[9];
  const float* hop_v    = (const float*)d_in[10];
  const float* w_ih     = (const float*)d_in[11];
  const float* w_hh     = (const float*)d_in[12];
  const float* b_ih     = (const float*)d_in[13];
  const float* b_hh     = (const float*)d_in[14];
  const float* gumbel   = (const float*)d_in[15];

  float* ws = (float*)d_ws;
  size_t fo = 0;
  const size_t FB = (size_t)NP * 512 / 2;
  ushort* hop_featT  = (ushort*)(ws + fo); fo += FB;
  ushort* attn_featT = (ushort*)(ws + fo); fo += FB;
  ushort* Ahi = (ushort*)(ws + fo); fo += FB;
  ushort* Alo = (ushort*)(ws + fo); fo += FB;
  ushort* WhiT_a = (ushort*)(ws + fo); fo += 131072;
  ushort* WloT_a = (ushort*)(ws + fo); fo += 131072;
  ushort* WhiT_h = (ushort*)(ws + fo); fo += 131072;
  ushort* WloT_h = (ushort*)(ws + fo); fo += 131072;
  int* sel   = (int*)(ws + fo); fo += NP;
  float* e   = ws + fo; fo += NP;
  float* bZ1 = ws + fo; fo += 1024;
  float* bZa = ws + fo; fo += 1024;
  float* bsc = ws + fo; fo += 1024;
  ull* bkey  = (ull*)(ws + fo); fo += 2048;
  float* hv0 = ws + fo; fo += HH;
  float* hv1 = ws + fo; fo += HH;
  float* cv0 = ws + fo; fo += HH;
  float* cv1 = ws + fo; fo += HH;
  float* b1  = ws + fo; fo += HH;
  float* b2  = ws + fo; fo += HH;
  float* qn  = ws + fo; fo += HH;
  float* Ztp = ws + fo; fo += 2;
  unsigned* cnts = (unsigned*)(ws + fo); fo += 128;
  int* done_buf = (int*)(ws + fo); fo += 2;
  int* xrow_buf = (int*)(ws + fo); fo += 2;
  if (fo * sizeof(float) > ws_size) return;

  float* outf = (float*)d_out;

  k_convA<<<(NP * 512 / 8) / 256, 256, 0, stream>>>(attn_mem, stoprow, Ahi, Alo, sel, cnts);
  k_convBT2<<<1024, 256, 0, stream>>>(attn_wm, hop_wm, WhiT_a, WloT_a, WhiT_h, WloT_h);

  dim3 ggrid(4, NP / 128);  // 1568 blocks = 8*196
  k_mfma<<<ggrid, 256, 0, stream>>>(Ahi, Alo, WhiT_a, WloT_a, attn_featT);
  k_mfma<<<ggrid, 256, 0, stream>>>(Ahi, Alo, WhiT_h, WloT_h, hop_featT);

  for (int t = 0; t < TT; ++t) {
    k_A<<<512, 256, 0, stream>>>(attn_mem, stoprow, init_i, init_h, init_c,
                                 w_ih, w_hh, b_ih, b_hh, hop_wq,
                                 hv0, hv1, cv0, cv1, b1, xrow_buf,
                                 cnts + 0, cnts + 16 + t, t);
    k_B1<<<NGC, 512, 0, stream>>>(hop_featT, b1, hop_v, e, bZ1, Ztp, cnts + 1);
    k_B2<<<512, 256, 0, stream>>>(hop_featT, e, Ztp, attn_wq, qn, b2,
                                  cnts + 3, cnts + 32 + t);
    k_C<<<NGC, 512, 0, stream>>>(attn_featT, b2, attn_v, sel,
                                 gumbel + (size_t)t * NROWS, bZa, bkey, bsc,
                                 done_buf, xrow_buf, outf, cnts + 2, t);
  }
}

// Round 19
// 1370.189 us; speedup vs baseline: 3.2908x; 1.1878x over previous
//
#include <hip/hip_runtime.h>
#include <math.h>

#define NITEMS 50000
#define NROWS 50001
#define NP 50176          // padded row count (392*128 = 196*256)
#define DD 512
#define HH 512
#define TT 16
#define NEGV (-1e18f)
#define NGRP 784          // 196 blocks x 4 partials
#define NGC 196           // transposed-sweep blocks (256 rows each)

typedef unsigned long long ull;
typedef unsigned short ushort;
typedef short short8 __attribute__((ext_vector_type(8)));
typedef float f32x4 __attribute__((ext_vector_type(4)));

// ---- scoped-atomic helpers (agent scope) ----
#define AST(p, v) __hip_atomic_store((p), (v), __ATOMIC_RELAXED, __HIP_MEMORY_SCOPE_AGENT)
#define ALD(p) __hip_atomic_load((p), __ATOMIC_RELAXED, __HIP_MEMORY_SCOPE_AGENT)
#define AADD_REL(p) __hip_atomic_fetch_add((p), 1u, __ATOMIC_ACQ_REL, __HIP_MEMORY_SCOPE_AGENT)
#define FLAG_SET(p) __hip_atomic_store((p), 1u, __ATOMIC_RELEASE, __HIP_MEMORY_SCOPE_AGENT)
#define FLAG_GET(p) __hip_atomic_load((p), __ATOMIC_ACQUIRE, __HIP_MEMORY_SCOPE_AGENT)

__device__ __forceinline__ unsigned fkey(float f) {
  unsigned u = __float_as_uint(f);
  return (u & 0x80000000u) ? ~u : (u | 0x80000000u);
}
__device__ __forceinline__ float ftanh(float x) {
  float e = __builtin_amdgcn_exp2f(x * 2.885390081777927f);
  return 1.f - 2.f * __builtin_amdgcn_rcpf(e + 1.f);
}
__device__ __forceinline__ float fexp(float x) {
  return __builtin_amdgcn_exp2f(x * 1.4426950408889634f);
}
__device__ __forceinline__ ushort rne1(float a) {
  unsigned u = __float_as_uint(a);
  return (ushort)((u + 0x7fffu + ((u >> 16) & 1u)) >> 16);
}
__device__ __forceinline__ float bf2f(ushort h) { return __uint_as_float((unsigned)h << 16); }
__device__ __forceinline__ unsigned pack_bf16(float a, float b) {
  return (unsigned)rne1(a) | ((unsigned)rne1(b) << 16);
}
__device__ __forceinline__ float bflo(unsigned u) { return __uint_as_float(u << 16); }
__device__ __forceinline__ float bfhi(unsigned u) { return __uint_as_float(u & 0xffff0000u); }

__device__ __forceinline__ void gl_lds16(const void* g, void* l) {
#if __has_builtin(__builtin_amdgcn_global_load_lds)
  __builtin_amdgcn_global_load_lds((const __attribute__((address_space(1))) unsigned*)g,
                                   (__attribute__((address_space(3))) unsigned*)l, 16, 0, 0);
#else
  const int lane = threadIdx.x & 63;
  *(uint4*)((char*)l + lane * 16) = *(const uint4*)g;
#endif
}

#define MFMA(a, b, c) __builtin_amdgcn_mfma_f32_16x16x32_bf16(a, b, c, 0, 0, 0)

// ---------------- A -> (Ahi, Alo) bf16 [NP][512]; also zeros sel + counters ----------------
__global__ void k_convA(const float* __restrict__ A0, const float* __restrict__ stoprow,
                        ushort* __restrict__ Ahi, ushort* __restrict__ Alo,
                        int* __restrict__ sel, unsigned* __restrict__ cnts) {
  const size_t t = (size_t)blockIdx.x * 256 + threadIdx.x;
  if (blockIdx.x < 196) {
    int i = blockIdx.x * 256 + threadIdx.x;
    if (i < NROWS) sel[i] = 0;
    if (blockIdx.x == 0 && threadIdx.x < 128) cnts[threadIdx.x] = 0;
  }
  const size_t base = t * 8;
  const int row = (int)(base >> 9);
  float v[8];
  if (row < NITEMS) {
    const float4* p = (const float4*)(A0 + base);
    float4 x = p[0], y = p[1];
    v[0] = x.x; v[1] = x.y; v[2] = x.z; v[3] = x.w;
    v[4] = y.x; v[5] = y.y; v[6] = y.z; v[7] = y.w;
  } else if (row == NITEMS) {
    const float4* p = (const float4*)(stoprow + (base & 511));
    float4 x = p[0], y = p[1];
    v[0] = x.x; v[1] = x.y; v[2] = x.z; v[3] = x.w;
    v[4] = y.x; v[5] = y.y; v[6] = y.z; v[7] = y.w;
  } else {
#pragma unroll
    for (int j = 0; j < 8; ++j) v[j] = 0.f;
  }
  unsigned hw[4], lw[4];
#pragma unroll
  for (int j = 0; j < 4; ++j) {
    float a0 = v[2 * j], a1 = v[2 * j + 1];
    ushort h0 = rne1(a0), h1 = rne1(a1);
    hw[j] = (unsigned)h0 | ((unsigned)h1 << 16);
    lw[j] = pack_bf16(a0 - bf2f(h0), a1 - bf2f(h1));
  }
  *(uint4*)(Ahi + base) = make_uint4(hw[0], hw[1], hw[2], hw[3]);
  *(uint4*)(Alo + base) = make_uint4(lw[0], lw[1], lw[2], lw[3]);
}

// ---------------- both W [k][n] -> transposed bf16 in one launch (1024 blocks) ----------------
__global__ void k_convBT2(const float* __restrict__ Wa, const float* __restrict__ Wh,
                          ushort* __restrict__ WhiT_a, ushort* __restrict__ WloT_a,
                          ushort* __restrict__ WhiT_h, ushort* __restrict__ WloT_h) {
  const int n = blockIdx.x & 511;
  const float* W = (blockIdx.x < 512) ? Wa : Wh;
  ushort* Whi = (blockIdx.x < 512) ? WhiT_a : WhiT_h;
  ushort* Wlo = (blockIdx.x < 512) ? WloT_a : WloT_h;
  const int k0 = threadIdx.x * 2;
  float a0 = W[(size_t)k0 * 512 + n];
  float a1 = W[(size_t)(k0 + 1) * 512 + n];
  ushort h0 = rne1(a0), h1 = rne1(a1);
  *(unsigned*)(Whi + (size_t)n * 512 + k0) = (unsigned)h0 | ((unsigned)h1 << 16);
  *(unsigned*)(Wlo + (size_t)n * 512 + k0) = pack_bf16(a0 - bf2f(h0), a1 - bf2f(h1));
}

// ---------------- MFMA GEMM (verified R10; swizzle exact: 1568 = 8*196) ----------------
__launch_bounds__(256, 2)
__global__ void k_mfma(const ushort* __restrict__ Ahi, const ushort* __restrict__ Alo,
                       const ushort* __restrict__ BhT, const ushort* __restrict__ BlT,
                       ushort* __restrict__ C) {
  __shared__ __align__(16) char lds[65536];
  char* sA0 = lds;
  char* sA1 = lds + 16384;
  char* sB0 = lds + 32768;
  char* sB1 = lds + 49152;
  const int tid = threadIdx.x;
  const int lane = tid & 63, w = tid >> 6;
  const int lid = blockIdx.y * 4 + blockIdx.x;
  const int xcd = lid & 7, pos = lid >> 3;
  const int orig = xcd * 196 + pos;
  const int m0 = (orig >> 2) * 128, n0 = (orig & 3) * 128;
  const int aR0 = (w & 1) * 64, bR0 = (w >> 1) * 64;

  f32x4 acc[4][4];
  const f32x4 z4 = {0.f, 0.f, 0.f, 0.f};
#pragma unroll
  for (int i = 0; i < 4; ++i)
#pragma unroll
    for (int j = 0; j < 4; ++j) acc[i][j] = z4;

#define STAGE_ALL(KT)                                                                     \
  {                                                                                       \
    _Pragma("unroll") for (int i = 0; i < 4; ++i) {                                       \
      const int row = i * 32 + (tid >> 3);                                                \
      const int kb = ((tid & 7) << 4) ^ ((row & 7) << 4);                                 \
      const int ldso = i * 4096 + (w << 10);                                              \
      gl_lds16((const char*)(Ahi + ((size_t)(m0 + row) << 9) + (KT)) + kb, sA0 + ldso);   \
      gl_lds16((const char*)(Alo + ((size_t)(m0 + row) << 9) + (KT)) + kb, sA1 + ldso);   \
      gl_lds16((const char*)(BhT + ((size_t)(n0 + row) << 9) + (KT)) + kb, sB0 + ldso);   \
      gl_lds16((const char*)(BlT + ((size_t)(n0 + row) << 9) + (KT)) + kb, sB1 + ldso);   \
    }                                                                                     \
  }

  STAGE_ALL(0)
  __syncthreads();
  for (int c = 0; c < 8; ++c) {
#pragma unroll
    for (int ks = 0; ks < 2; ++ks) {
      short8 ah[4], al[4], bh[4], bl[4];
      const int kbb = ks * 64 + ((lane >> 4) << 4);
#pragma unroll
      for (int f = 0; f < 4; ++f) {
        const int ra = aR0 + f * 16 + (lane & 15);
        const int oa = ra * 128 + (kbb ^ ((ra & 7) << 4));
        ah[f] = *(const short8*)(sA0 + oa);
        al[f] = *(const short8*)(sA1 + oa);
        const int rb = bR0 + f * 16 + (lane & 15);
        const int ob = rb * 128 + (kbb ^ ((rb & 7) << 4));
        bh[f] = *(const short8*)(sB0 + ob);
        bl[f] = *(const short8*)(sB1 + ob);
      }
#pragma unroll
      for (int mf = 0; mf < 4; ++mf)
#pragma unroll
        for (int nf = 0; nf < 4; ++nf) {
          acc[mf][nf] = MFMA(ah[mf], bh[nf], acc[mf][nf]);
          acc[mf][nf] = MFMA(ah[mf], bl[nf], acc[mf][nf]);
          acc[mf][nf] = MFMA(al[mf], bh[nf], acc[mf][nf]);
        }
    }
    if (c < 7) {
      __syncthreads();
      STAGE_ALL((c + 1) * 64)
      __syncthreads();
    }
  }
#undef STAGE_ALL

#pragma unroll
  for (int mf = 0; mf < 4; ++mf)
#pragma unroll
    for (int nf = 0; nf < 4; ++nf) {
      const f32x4 a = acc[mf][nf];
      const int n = n0 + bR0 + nf * 16 + (lane & 15);
      const int mb = m0 + aR0 + mf * 16 + ((lane >> 4) << 2);
      ushort* p = C + (size_t)n * NP + mb;
      *(uint2*)p = make_uint2(pack_bf16(a.x, a.y), pack_bf16(a.z, a.w));
    }
}

// ================= A: LSTM gates + h,c; last-16 blocks: b1 slices =================
__launch_bounds__(256)
__global__ void k_A(const float* __restrict__ attn_mem, const float* __restrict__ stoprow,
                    const float* __restrict__ init_i, const float* __restrict__ init_h,
                    const float* __restrict__ init_c,
                    const float* __restrict__ w_ih, const float* __restrict__ w_hh,
                    const float* __restrict__ b_ih, const float* __restrict__ b_hh,
                    const float* __restrict__ hop_wq,
                    float* __restrict__ hv0, float* __restrict__ hv1,
                    float* __restrict__ cv0, float* __restrict__ cv1,
                    float* __restrict__ b1, const int* __restrict__ xrow_buf,
                    unsigned* __restrict__ cntA, unsigned* __restrict__ flagA, int t) {
  __shared__ float g4[4];
  __shared__ float hs[512];
  __shared__ float red2[256];
  __shared__ int sOld;
  const int b = blockIdx.x, tid = threadIdx.x, w = tid >> 6, lane = tid & 63;
  const int xrow = (t == 0) ? -1 : ALD((int*)xrow_buf);
  const float* xp = (xrow < 0) ? init_i
                               : ((xrow == NITEMS) ? stoprow : attn_mem + (size_t)xrow * DD);
  const float* hsrc = (t == 0) ? init_h : ((t & 1) ? hv0 : hv1);
  float* hdst = (t & 1) ? hv1 : hv0;
  const float* csrc = (t == 0) ? init_c : ((t & 1) ? cv0 : cv1);
  float* cdst = (t & 1) ? cv1 : cv0;

  const int r = w * 512 + b;
  const float4* x4 = (const float4*)xp;
  const float4* h4 = (const float4*)hsrc;
  const float4* wi = (const float4*)(w_ih + (size_t)r * DD);
  const float4* wh = (const float4*)(w_hh + (size_t)r * DD);
  float s = 0.f;
  float4 a, ww;
  a = x4[lane * 2];     ww = wi[lane * 2];     s += a.x * ww.x + a.y * ww.y + a.z * ww.z + a.w * ww.w;
  a = x4[lane * 2 + 1]; ww = wi[lane * 2 + 1]; s += a.x * ww.x + a.y * ww.y + a.z * ww.z + a.w * ww.w;
  a = h4[lane * 2];     ww = wh[lane * 2];     s += a.x * ww.x + a.y * ww.y + a.z * ww.z + a.w * ww.w;
  a = h4[lane * 2 + 1]; ww = wh[lane * 2 + 1]; s += a.x * ww.x + a.y * ww.y + a.z * ww.z + a.w * ww.w;
#pragma unroll
  for (int off = 32; off > 0; off >>= 1) s += __shfl_xor(s, off);
  if (lane == 0) g4[w] = s + b_ih[r] + b_hh[r];
  __syncthreads();
  if (tid == 0) {
    const float si = 1.f / (1.f + expf(-g4[0]));
    const float sf = 1.f / (1.f + expf(-g4[1]));
    const float so = 1.f / (1.f + expf(-g4[3]));
    const float cn = sf * csrc[b] + si * tanhf(g4[2]);
    cdst[b] = cn;
    AST(&hdst[b], so * tanhf(cn));
  }
  __syncthreads();
  if (tid == 0) {
    unsigned old = AADD_REL(cntA);
    if (old == 511u) { FLAG_SET(flagA); AST(cntA, 0u); }
    sOld = (int)old;
  }
  __syncthreads();
  const int old = sOld;
  if (old >= 496) {
    if (tid == 0 && old != 511) {
      while (FLAG_GET(flagA) == 0u) __builtin_amdgcn_s_sleep(2);
    }
    __syncthreads();
    const int c0 = (old - 496) * 32;
    hs[tid] = ALD(&hdst[tid]);
    hs[tid + 256] = ALD(&hdst[tid + 256]);
    __syncthreads();
    const int col = c0 + (tid & 31), seg = tid >> 5;
    float acc = 0.f;
#pragma unroll 8
    for (int i = seg * 64; i < seg * 64 + 64; ++i)
      acc = fmaf(hs[i], hop_wq[(size_t)i * 512 + col], acc);
    red2[tid] = acc;
    __syncthreads();
    if (tid < 32) {
      float sm = 0.f;
#pragma unroll
      for (int g2 = 0; g2 < 8; ++g2) sm += red2[tid + 32 * g2];
      b1[c0 + tid] = sm;
    }
  }
}

// ================= B (fused): hop scores -> e (LDS) -> block-local qp partial;
//                  tail-16: Zt + qn combine -> micro-sync -> b2 slices =================
__launch_bounds__(512)
__global__ void k_B(const ushort* __restrict__ featT, const float* __restrict__ b1v,
                    const float* __restrict__ hv, const float* __restrict__ attn_wq,
                    float* __restrict__ qp, float* __restrict__ bZ1,
                    float* __restrict__ qn, float* __restrict__ b2,
                    unsigned* __restrict__ cnt1, unsigned* __restrict__ cnt2,
                    unsigned* __restrict__ flagQ, unsigned* __restrict__ flagB2) {
  __shared__ float spart[8][256];
  __shared__ float e_lds[256];
  __shared__ float red[512];
  __shared__ int sOld;
  const int tid = threadIdx.x, g = blockIdx.x;
  const int w = tid >> 6, lane = tid & 63;
  const int mb0 = g * 256;

  // ---- phase 1: scores for rows [mb0, mb0+256) ----
  {
    const int mb = mb0 + lane * 4;
    const int h0 = w * 64;
    const ushort* fp = featT + (size_t)h0 * NP + mb;
    float a0 = 0.f, a1 = 0.f, a2 = 0.f, a3 = 0.f;
#pragma unroll 8
    for (int hh = 0; hh < 64; ++hh) {
      const uint2 u = *(const uint2*)fp;
      fp += NP;
      const float bb = b1v[h0 + hh], vv = hv[h0 + hh];
      a0 += ftanh(bflo(u.x) + bb) * vv;
      a1 += ftanh(bfhi(u.x) + bb) * vv;
      a2 += ftanh(bflo(u.y) + bb) * vv;
      a3 += ftanh(bfhi(u.y) + bb) * vv;
    }
    spart[w][lane * 4 + 0] = a0;
    spart[w][lane * 4 + 1] = a1;
    spart[w][lane * 4 + 2] = a2;
    spart[w][lane * 4 + 3] = a3;
  }
  __syncthreads();
  if (w < 4) {
    const int idx = w * 64 + lane;
    const int m = mb0 + idx;
    float s = 0.f;
#pragma unroll
    for (int w2 = 0; w2 < 8; ++w2) s += spart[w2][idx];
    float ev = (m < NROWS) ? fexp(s) : 0.f;
    e_lds[idx] = ev;
    float Z = ev;
#pragma unroll
    for (int off = 32; off > 0; off >>= 1) Z += __shfl_xor(Z, off);
    if (lane == 0) AST(&bZ1[g * 4 + w], Z);
  }
  __syncthreads();

  // ---- phase 2: block-local qp partial; thread owns h = tid (L2-hot tile re-read) ----
  {
    const ushort* fr = featT + (size_t)tid * NP + mb0;
    float acc = 0.f;
#pragma unroll 4
    for (int j = 0; j < 256; j += 8) {
      const uint4 F = *(const uint4*)(fr + j);
      acc += bflo(F.x) * e_lds[j + 0] + bfhi(F.x) * e_lds[j + 1] +
             bflo(F.y) * e_lds[j + 2] + bfhi(F.y) * e_lds[j + 3] +
             bflo(F.z) * e_lds[j + 4] + bfhi(F.z) * e_lds[j + 5] +
             bflo(F.w) * e_lds[j + 6] + bfhi(F.w) * e_lds[j + 7];
    }
    AST(&qp[(size_t)g * 512 + tid], acc);
  }
  __syncthreads();

  // ---- arrival counter; tail = last 16 arrivers ----
  if (tid == 0) {
    unsigned old = AADD_REL(cnt1);
    if (old == NGC - 1u) { FLAG_SET(flagQ); AST(cnt1, 0u); }
    sOld = (int)old;
  }
  __syncthreads();
  const int old = sOld;
  if (old >= NGC - 16) {
    if (tid == 0 && old != NGC - 1) {
      while (FLAG_GET(flagQ) == 0u) __builtin_amdgcn_s_sleep(2);
    }
    __syncthreads();
    // Zt (redundant per tail block)
    float zl = 0.f;
    for (int i = tid; i < NGRP; i += 512) zl += ALD(&bZ1[i]);
    red[tid] = zl;
    __syncthreads();
    for (int s2 = 256; s2 > 0; s2 >>= 1) {
      if (tid < s2) red[tid] += red[tid + s2];
      __syncthreads();
    }
    const float Zt = red[0];
    __syncthreads();
    const int li = old - (NGC - 16);
    // qn slice [li*32, +32): 16 segs over 196 partials
    {
      const int h = li * 32 + (tid & 31), seg = tid >> 5;
      float a = 0.f;
      for (int g2 = seg; g2 < NGC; g2 += 16) a += ALD(&qp[(size_t)g2 * 512 + h]);
      red[tid] = a;
      __syncthreads();
      if (tid < 32) {
        float sm = 0.f;
#pragma unroll
        for (int s2 = 0; s2 < 16; ++s2) sm += red[tid + 32 * s2];
        AST(&qn[li * 32 + tid], sm / Zt);
      }
    }
    __syncthreads();
    // micro-sync among the 16 tail blocks
    if (tid == 0) {
      unsigned o2 = AADD_REL(cnt2);
      if (o2 == 15u) { FLAG_SET(flagB2); AST(cnt2, 0u); }
      else { while (FLAG_GET(flagB2) == 0u) __builtin_amdgcn_s_sleep(2); }
    }
    __syncthreads();
    // b2 slice [li*32, +32): 16 segs x 32 rows
    {
      const int j = li * 32 + (tid & 31), seg = tid >> 5;
      float a = 0.f;
#pragma unroll 8
      for (int i2 = seg * 32; i2 < seg * 32 + 32; ++i2)
        a = fmaf(ALD(&qn[i2]), attn_wq[(size_t)i2 * 512 + j], a);
      red[tid] = a;
      __syncthreads();
      if (tid < 32) {
        float sm = 0.f;
#pragma unroll
        for (int s2 = 0; s2 < 16; ++s2) sm += red[tid + 32 * s2];
        b2[li * 32 + tid] = sm;
      }
    }
  }
}

// ================= C: attn transposed sweep; score carried with key; last block: sample =================
__launch_bounds__(512)
__global__ void k_C(const ushort* __restrict__ featT, const float* __restrict__ b2,
                    const float* __restrict__ av, int* __restrict__ sel,
                    const float* __restrict__ gum,
                    float* __restrict__ bZa, ull* __restrict__ bkey, float* __restrict__ bsc,
                    int* __restrict__ done_buf, int* __restrict__ xrow_buf,
                    float* __restrict__ outf, unsigned* __restrict__ cntC, int t) {
  __shared__ float spart[8][256];
  __shared__ float rz[512];
  __shared__ ull rk[512];
  __shared__ float rs[512];
  __shared__ int isLast;
  const int tid = threadIdx.x, g = blockIdx.x;
  const int w = tid >> 6, lane = tid & 63;
  const int mb = g * 256 + lane * 4;
  const int h0 = w * 64;
  const ushort* fp = featT + (size_t)h0 * NP + mb;
  float a0 = 0.f, a1 = 0.f, a2 = 0.f, a3 = 0.f;
#pragma unroll 8
  for (int hh = 0; hh < 64; ++hh) {
    const uint2 u = *(const uint2*)fp;
    fp += NP;
    const float bb = b2[h0 + hh], vv = av[h0 + hh];
    a0 += ftanh(bflo(u.x) + bb) * vv;
    a1 += ftanh(bfhi(u.x) + bb) * vv;
    a2 += ftanh(bflo(u.y) + bb) * vv;
    a3 += ftanh(bfhi(u.y) + bb) * vv;
  }
  spart[w][lane * 4 + 0] = a0;
  spart[w][lane * 4 + 1] = a1;
  spart[w][lane * 4 + 2] = a2;
  spart[w][lane * 4 + 3] = a3;
  __syncthreads();
  if (w < 4) {
    const int idx = w * 64 + lane;
    const int m = g * 256 + idx;
    float s = 0.f;
#pragma unroll
    for (int w2 = 0; w2 < 8; ++w2) s += spart[w2][idx];
    const bool valid = (m < NROWS);
    float Z, sv;
    ull key;
    if (valid) {
      const float se = sel[m] ? NEGV : s;
      sv = se;
      key = ((ull)fkey(se + gum[m]) << 32) | (unsigned)(NITEMS - m);
      Z = fexp(se);
    } else {
      key = 0;
      Z = 0.f;
      sv = 0.f;
    }
#pragma unroll
    for (int off = 32; off > 0; off >>= 1) {
      Z += __shfl_xor(Z, off);
      ull Ko = __shfl_xor(key, off);
      float so = __shfl_xor(sv, off);
      if (Ko > key) { key = Ko; sv = so; }
    }
    if (lane == 0) {
      AST(&bZa[g * 4 + w], Z);
      AST(&bkey[g * 4 + w], key);
      AST(&bsc[g * 4 + w], sv);
    }
  }
  __syncthreads();
  if (tid == 0) {
    unsigned old = AADD_REL(cntC);
    isLast = (old == gridDim.x - 1);
    if (isLast) AST(cntC, 0u);
  }
  __syncthreads();
  if (isLast) {
    float Zl = 0.f, Sl = 0.f;
    ull Kl = 0;
    for (int i = tid; i < NGRP; i += 512) {
      Zl += ALD(&bZa[i]);
      ull k = ALD(&bkey[i]);
      if (k > Kl) { Kl = k; Sl = ALD(&bsc[i]); }
    }
    rz[tid] = Zl;
    rk[tid] = Kl;
    rs[tid] = Sl;
    __syncthreads();
    for (int s2 = 256; s2 > 0; s2 >>= 1) {
      if (tid < s2) {
        rz[tid] += rz[tid + s2];
        if (rk[tid + s2] > rk[tid]) { rk[tid] = rk[tid + s2]; rs[tid] = rs[tid + s2]; }
      }
      __syncthreads();
    }
    if (tid == 0) {
      const float Z = rz[0];
      const ull K = rk[0];
      const int out = NITEMS - (int)(unsigned)(K & 0xffffffffull);
      const int d_in = (t == 0) ? 0 : *done_buf;
      const int xprev = (t == 0) ? -1 : *xrow_buf;
      const int nd = d_in | (out == NITEMS);
      outf[t] = (float)(d_in ? NITEMS : out);
      outf[TT + t] = d_in ? 0.f : (rs[0] - logf(Z));
      if (!d_in) sel[out] = 1;
      *done_buf = nd;
      *xrow_buf = nd ? xprev : out;
    }
  }
}

// ======================================================================
extern "C" void kernel_launch(void* const* d_in, const int* in_sizes, int n_in,
                              void* d_out, int out_size, void* d_ws, size_t ws_size,
                              hipStream_t stream) {
  const float* attn_mem = (const float*)d_in[0];
  const float* stoprow  = (const float*)d_in[1];
  const float* init_h   = (const float*)d_in[2];
  const float* init_c   = (const float*)d_in[3];
  const float* init_i   = (const float*)d_in[4];
  const float* attn_wm  = (const float*)d_in[5];
  const float* attn_wq  = (const float*)d_in[6];
  const float* attn_v   = (const float*)d_in[7];
  const float* hop_wm   = (const float*)d_in[8];
  const float* hop_wq   = (const float*)d_in[9];
  const float* hop_v    = (const float*)d_in[10];
  const float* w_ih     = (const float*)d_in[11];
  const float* w_hh     = (const float*)d_in[12];
  const float* b_ih     = (const float*)d_in[13];
  const float* b_hh     = (const float*)d_in[14];
  const float* gumbel   = (const float*)d_in[15];

  float* ws = (float*)d_ws;
  size_t fo = 0;
  const size_t FB = (size_t)NP * 512 / 2;
  ushort* hop_featT  = (ushort*)(ws + fo); fo += FB;
  ushort* attn_featT = (ushort*)(ws + fo); fo += FB;
  ushort* Ahi = (ushort*)(ws + fo); fo += FB;
  ushort* Alo = (ushort*)(ws + fo); fo += FB;
  ushort* WhiT_a = (ushort*)(ws + fo); fo += 131072;
  ushort* WloT_a = (ushort*)(ws + fo); fo += 131072;
  ushort* WhiT_h = (ushort*)(ws + fo); fo += 131072;
  ushort* WloT_h = (ushort*)(ws + fo); fo += 131072;
  int* sel   = (int*)(ws + fo); fo += NP;
  float* qp  = ws + fo; fo += (size_t)NGC * 512;
  float* bZ1 = ws + fo; fo += 1024;
  float* bZa = ws + fo; fo += 1024;
  float* bsc = ws + fo; fo += 1024;
  ull* bkey  = (ull*)(ws + fo); fo += 2048;
  float* hv0 = ws + fo; fo += HH;
  float* hv1 = ws + fo; fo += HH;
  float* cv0 = ws + fo; fo += HH;
  float* cv1 = ws + fo; fo += HH;
  float* b1  = ws + fo; fo += HH;
  float* b2  = ws + fo; fo += HH;
  float* qn  = ws + fo; fo += HH;
  unsigned* cnts = (unsigned*)(ws + fo); fo += 128;
  int* done_buf = (int*)(ws + fo); fo += 2;
  int* xrow_buf = (int*)(ws + fo); fo += 2;
  if (fo * sizeof(float) > ws_size) return;

  float* outf = (float*)d_out;

  k_convA<<<(NP * 512 / 8) / 256, 256, 0, stream>>>(attn_mem, stoprow, Ahi, Alo, sel, cnts);
  k_convBT2<<<1024, 256, 0, stream>>>(attn_wm, hop_wm, WhiT_a, WloT_a, WhiT_h, WloT_h);

  dim3 ggrid(4, NP / 128);  // 1568 blocks = 8*196
  k_mfma<<<ggrid, 256, 0, stream>>>(Ahi, Alo, WhiT_a, WloT_a, attn_featT);
  k_mfma<<<ggrid, 256, 0, stream>>>(Ahi, Alo, WhiT_h, WloT_h, hop_featT);

  for (int t = 0; t < TT; ++t) {
    k_A<<<512, 256, 0, stream>>>(attn_mem, stoprow, init_i, init_h, init_c,
                                 w_ih, w_hh, b_ih, b_hh, hop_wq,
                                 hv0, hv1, cv0, cv1, b1, xrow_buf,
                                 cnts + 0, cnts + 48 + t, t);
    k_B<<<NGC, 512, 0, stream>>>(hop_featT, b1, hop_v, attn_wq, qp, bZ1, qn, b2,
                                 cnts + 1, cnts + 3, cnts + 16 + t, cnts + 32 + t);
    k_C<<<NGC, 512, 0, stream>>>(attn_featT, b2, attn_v, sel,
                                 gumbel + (size_t)t * NROWS, bZa, bkey, bsc,
                                 done_buf, xrow_buf, outf, cnts + 2, t);
  }
}